// Round 14
// baseline (137.510 us; speedup 1.0000x reference)
//
#include <hip/hip_runtime.h>
#include <hip/hip_bf16.h>
#include <math.h>

// EntropyInvarianceAttention: out = softmax(c * Q^T K) V^T per (b,h),
// c = ln(k_length[b]) / (8*ln(20)); q,k,v are (B, 512, 2048) fp32, l contiguous.
//
// R21 = R20 (VERIFIED WIN: attn 58.4->49.4us via 1-instr asm cvt_pk; total
// 134.5us; 512x512, 8 waves = 4 q-subtiles x 2 k-halves, 3-stage LDS,
// proven sync) + EXACTLY ONE delta:
//  - lsum: 16 VALU adds/tile -> 2 ones-A MFMAs on the 72%-idle matrix pipe.
//    A[m=l31][k=hi*8+j], row0=ones (l31==0 lanes) => D[0][q]=sum_k P[k][q];
//    C row0 lives in reg 0 of hi=0 lanes. Epilogue: fb[32]=lacc[0] (valid on
//    hi=0), final broadcast __shfl(lsc, l31, 64) reads lane l31<32 (hi=0) so
//    hi=1 garbage never propagates.
//  - This was R19's FIX3; R19 failed because of its raw-asm v_exp_f32
//    (missing trans-op hazard waits), now attributed: R20 passed with the
//    same cvt_pk asm + builtin exp. Testing FIX3 as a single delta.
// Prep (R13 fused) and fallback unchanged.

typedef __attribute__((ext_vector_type(8))) short short8_t;
typedef __attribute__((ext_vector_type(4))) short short4_t;
typedef __attribute__((ext_vector_type(4))) float float4_t;
typedef __attribute__((ext_vector_type(16))) float float16_t;

#define SEQ   2048
#define NBH   32
#define NKT   32

// pack two f32 -> one u32 of 2 bf16 (lo = a, hi = b), single instruction.
// T12/m201/m214 recipe (HW-refcheck'd); no builtin exists on gfx950.
__device__ __forceinline__ unsigned f2bf2u(float a, float b) {
  unsigned r;
  asm("v_cvt_pk_bf16_f32 %0, %1, %2" : "=v"(r) : "v"(a), "v"(b));
  return r;
}

__device__ __forceinline__ short f2bf1(float a) {
  return (short)(f2bf2u(a, a) & 0xffffu);
}

// 2^x via the builtin: compiler knows the trans-op hazard rules (R19 lesson:
// raw asm v_exp_f32 -> missing wait states -> stale reads -> wrong output).
__device__ __forceinline__ float fast_exp2(float x) {
#if __has_builtin(__builtin_amdgcn_exp2f)
  return __builtin_amdgcn_exp2f(x);
#else
  return exp2f(x);
#endif
}

__device__ __forceinline__ void gld16(const void* g, void* l) {
  __builtin_amdgcn_global_load_lds(
      (const __attribute__((address_space(1))) void*)g,
      (__attribute__((address_space(3))) void*)l, 16, 0, 0);
}

__device__ __forceinline__ float4_t mfma32(short8_t a, short8_t b, float4_t c) {
  return __builtin_amdgcn_mfma_f32_16x16x32_bf16(a, b, c, 0, 0, 0);
}

__device__ __forceinline__ float16_t mfma3232(short8_t a, short8_t b, float16_t c) {
  return __builtin_amdgcn_mfma_f32_32x32x16_bf16(a, b, c, 0, 0, 0);
}

// lane<32/lane>=32 half exchange: a' = [a_lo|b_lo], b' = [a_hi|b_hi]
__device__ __forceinline__ void plswap(unsigned& a, unsigned& b, int hi) {
#if __has_builtin(__builtin_amdgcn_permlane32_swap)
  typedef __attribute__((ext_vector_type(2))) unsigned uint2_t;
  uint2_t r = __builtin_amdgcn_permlane32_swap(a, b, false, false);
  a = r[0]; b = r[1];
#else
  const unsigned sa = (unsigned)__shfl_xor((int)a, 32);
  const unsigned sb = (unsigned)__shfl_xor((int)b, 32);
  const unsigned an = hi ? sb : a;
  const unsigned bn = hi ? b : sa;
  a = an; b = bn;
#endif
}

// ---------------- fused pre-pass (R13): one block per (bh,kt) ----------
// K -> Kt2[bh][kt][ch(8)][lr(64)][8]: out[ch*512+lr*8+j] = K[d=ch*8+j][k=lr]
// V -> Vt3[bh][kt][kc(8)][d(64)][8]:  out[(kc*64+d)*8+j] = V[d][k=kc*8+j]
#define PST 68
__global__ __launch_bounds__(256, 8)
void eia_prep_kernel(const float* __restrict__ kg, const float* __restrict__ vg,
                     unsigned short* __restrict__ Kt2, unsigned short* __restrict__ Vt2) {
  __shared__ __align__(16) short T[64 * PST];
  const int bh = blockIdx.x >> 5;
  const int kt = blockIdx.x & 31;
  const int t  = threadIdx.x;

  // ---- K phase: float4 loads along k, scatter bf16 to T[k][d] ----
  {
    const int dr = t >> 4;          // 0..15
    const int kq = (t & 15) * 4;    // 0,4,..,60
#pragma unroll
    for (int i = 0; i < 4; ++i) {
      const int d = i * 16 + dr;
      const float4_t f = *(const float4_t*)
          &kg[((size_t)bh * 64 + d) * SEQ + (size_t)(kt * 64 + kq)];
      T[(kq + 0) * PST + d] = f2bf1(f[0]);
      T[(kq + 1) * PST + d] = f2bf1(f[1]);
      T[(kq + 2) * PST + d] = f2bf1(f[2]);
      T[(kq + 3) * PST + d] = f2bf1(f[3]);
    }
  }
  __syncthreads();
  // K writeout (byte-identical to proven layout)
  {
    unsigned short* outt = Kt2 + (size_t)(bh * 32 + kt) * 4096;
#pragma unroll
    for (int rep = 0; rep < 2; ++rep) {
      const int id2 = rep * 256 + t;
      const int lr = id2 & 63, ch = id2 >> 6;
      union { short8_t v; short4_t h[2]; } o;
      o.h[0] = *(const short4_t*)&T[lr * PST + ch * 8];
      o.h[1] = *(const short4_t*)&T[lr * PST + ch * 8 + 4];
      *(short8_t*)&outt[ch * 512 + lr * 8] = o.v;
    }
  }
  __syncthreads();  // K reads of T done before V overwrites

  // ---- V phase: float4 loads along k into T[d][k] (proven pattern) ----
#pragma unroll
  for (int rep = 0; rep < 4; ++rep) {
    const int id2 = rep * 256 + t;
    const int d = id2 >> 4, l4 = (id2 & 15) * 4;
    const float4_t f = *(const float4_t*)
        &vg[((size_t)bh * 64 + d) * SEQ + (size_t)(kt * 64 + l4)];
    union { short4_t s; unsigned u[2]; } p;
    p.u[0] = f2bf2u(f[0], f[1]);
    p.u[1] = f2bf2u(f[2], f[3]);
    *(short4_t*)&T[d * PST + l4] = p.s;
  }
  __syncthreads();
  // Vt3 writeout (byte-identical to R12)
  {
    unsigned short* outt = Vt2 + (size_t)(bh * 32 + kt) * 4096;
#pragma unroll
    for (int rep = 0; rep < 2; ++rep) {
      const int c = rep * 256 + t;
      const int kc = c >> 6, d = c & 63;
      union { short8_t v; short4_t h[2]; } o;
      o.h[0] = *(const short4_t*)&T[d * PST + kc * 8];
      o.h[1] = *(const short4_t*)&T[d * PST + kc * 8 + 4];
      *(short8_t*)&outt[c * 8] = o.v;
    }
  }
}

// ---------------- main fused attention (R21: R20 + ones-MFMA lsum) --------
// LDS (shorts): K stages [0,4096)|[4096,8192)|[8192,12288)
//               V stages [12288,16384)|[16384,20480)|[20480,24576)
// Q staging overlays [0, 8704); epilogue floats [0, 34816 B) after the loop.
__global__ __launch_bounds__(512, 4)
void eia_attn_kernel(const float* __restrict__ qg,
                     const unsigned short* __restrict__ Kt2,
                     const unsigned short* __restrict__ Vt2,
                     const int* __restrict__ klen,
                     float* __restrict__ outg) {
  __shared__ __align__(16) short SM[24576];

  const int tid   = threadIdx.x;
  const int bh    = blockIdx.x & 31;   // XCD = bh%8; 512 blocks = 2/CU
  const int qt    = blockIdx.x >> 5;
  const int q0    = qt * 128;
  const int wv    = tid >> 6;          // wave 0..7
  const int qw    = wv & 3;            // q-subtile (32 q)
  const int h     = wv >> 2;           // k-half: S-tile kb=h, ks=2h..2h+1
  const int lane  = tid & 63;
  const int l31   = lane & 31;
  const int hi    = lane >> 5;

  const float c = (1.4426950408889634f / (8.0f * 2.9957322735539909f)) *
                  logf((float)klen[bh >> 3]);
  const size_t qb = (size_t)bh * 64 * SEQ;

  // ---- Q stage: fp32 global -> SM[q][d] bf16 (stride 68), c folded ----
#pragma unroll
  for (int rep = 0; rep < 4; ++rep) {
    const int id = rep * 512 + tid;       // 0..2047
    const int d  = id >> 5;               // 0..63
    const int q4 = (id & 31) * 4;
    const float4_t f = *(const float4_t*)&qg[qb + (size_t)d * SEQ + (size_t)(q0 + q4)];
    SM[(q4 + 0) * 68 + d] = f2bf1(c * f[0]);
    SM[(q4 + 1) * 68 + d] = f2bf1(c * f[1]);
    SM[(q4 + 2) * 68 + d] = f2bf1(c * f[2]);
    SM[(q4 + 3) * 68 + d] = f2bf1(c * f[3]);
  }
  __syncthreads();

  // Q B-fragments (32x32x16 B-layout): B[d=s*16+hi*8+j][q=l31], s=0..3
  short8_t qfrag[4];
#pragma unroll
  for (int s = 0; s < 4; ++s) {
    const short* qp = &SM[(qw * 32 + l31) * 68 + s * 16 + hi * 8];
    const short4_t lo = *(const short4_t*)qp;
    const short4_t hh = *(const short4_t*)(qp + 4);
    qfrag[s] = short8_t{lo[0], lo[1], lo[2], lo[3], hh[0], hh[1], hh[2], hh[3]};
  }
  __syncthreads();  // Q reads done before DMA overwrites SM

  // ones A-fragment for lsum MFMA: A[m=l31][k=hi*8+j]; row 0 = ones.
  const short one_bf = (short)0x3F80;
  const short8_t a_ones = (l31 == 0)
      ? short8_t{one_bf, one_bf, one_bf, one_bf, one_bf, one_bf, one_bf, one_bf}
      : short8_t{0, 0, 0, 0, 0, 0, 0, 0};

  // ---- DMA setup: tile = 16 x 1KB instrs (8 K + 8 V) over 8 waves ----
  const char* ksrc = (const char*)Kt2 + (size_t)bh * NKT * 8192 + wv * 1024 + lane * 16;
  const char* vsrc = (const char*)Vt2 + (size_t)bh * NKT * 8192 + wv * 1024 + lane * 16;
  short* const kdst = &SM[wv * 512];            // + stage*4096 (HW adds lane*16B)
  short* const vdst = &SM[12288 + wv * 512];

  // per-lane invariant fragment offsets (shorts)
  const int lofs = hi * 512 + l31 * 8;
  const short* const kfp = &SM[lofs + h * 256];   // + koff + s*1024
  const short* const vfp = &SM[12288 + lofs];     // + koff + ks*1024 + dt*256

  const float16_t z16 = {0.f,0.f,0.f,0.f,0.f,0.f,0.f,0.f,
                         0.f,0.f,0.f,0.f,0.f,0.f,0.f,0.f};
  float16_t oacc0 = z16, oacc1 = z16;   // dt = 0,1 (k-half partials)
  float16_t lacc = z16;                 // lacc[0] (hi=0) = sum_k P[k][q=l31]

  // ---- prologue: DMA tiles 0,1 -> stages 0,1 (2 loads/wave/tile) ----
  gld16(ksrc, kdst);               gld16(vsrc, vdst);
  gld16(ksrc + 8192, kdst + 4096); gld16(vsrc + 8192, vdst + 4096);
  // One-time full drain: no issue-order assumption on prologue loads.
  asm volatile("s_waitcnt vmcnt(0)" ::: "memory");

  int  sc = 0;              // stage (shorts offset/4096) of current tile
  int  sn = 2;              // stage of tile kt+2
  size_t gsrc = 2 * 8192;   // byte offset of tile kt+2

  for (int kt = 0; kt < NKT; ++kt) {
    // wait: current tile's 2 loads done; NEXT tile's 2 stay in flight.
    if (kt < NKT - 1) asm volatile("s_waitcnt vmcnt(2)" ::: "memory");
    else              asm volatile("s_waitcnt vmcnt(0)" ::: "memory");
    asm volatile("s_barrier" ::: "memory");

    // issue DMA for tile kt+2 into stage sn
    if (kt < NKT - 2) {
      const int so = sn * 4096;
      gld16(ksrc + gsrc, kdst + so);
      gld16(vsrc + gsrc, vdst + so);
      gsrc += 8192;
      sn = (sn == 2) ? 0 : sn + 1;
    }
    const int koff = sc * 4096;
    sc = (sc == 2) ? 0 : sc + 1;
    const short* const kb_ = kfp + koff;
    const short* const vb_ = vfp + koff;

    // ---- S^T = K^T * Q (this wave's kb-half): 4 chained mfma_32x32x16 ----
    float16_t s0 = z16;
#pragma unroll
    for (int s = 0; s < 4; ++s)
      s0 = mfma3232(*(const short8_t*)(kb_ + s * 1024), qfrag[s], s0);

    // ---- exp (builtin) + cvt_pk (1 instr) + permlane repack ----
    union pfu { short8_t s8; unsigned u[4]; };
    pfu pf[2];
#pragma unroll
    for (int ksl = 0; ksl < 2; ++ksl) {
      const int b = ksl * 8;
      unsigned a02 = f2bf2u(fast_exp2(s0[b + 0]), fast_exp2(s0[b + 1]));
      unsigned b02 = f2bf2u(fast_exp2(s0[b + 4]), fast_exp2(s0[b + 5]));
      unsigned a13 = f2bf2u(fast_exp2(s0[b + 2]), fast_exp2(s0[b + 3]));
      unsigned b13 = f2bf2u(fast_exp2(s0[b + 6]), fast_exp2(s0[b + 7]));
      plswap(a02, b02, hi);
      plswap(a13, b13, hi);
      pf[ksl].u[0] = a02;
      pf[ksl].u[1] = a13;
      pf[ksl].u[2] = b02;
      pf[ksl].u[3] = b13;
    }
    // lsum on the idle matrix pipe: D[0][q] += sum_k P[k][q]
    lacc = mfma3232(a_ones, pf[0].s8, lacc);
    lacc = mfma3232(a_ones, pf[1].s8, lacc);

    // ---- O^T += V * P^T (ks = 2h+ksl): 2 dt x 2 chained mfma_32x32x16 ----
#pragma unroll
    for (int ksl = 0; ksl < 2; ++ksl)
      oacc0 = mfma3232(*(const short8_t*)(vb_ + (h * 2 + ksl) * 1024),
                       pf[ksl].s8, oacc0);
#pragma unroll
    for (int ksl = 0; ksl < 2; ++ksl)
      oacc1 = mfma3232(*(const short8_t*)(vb_ + 256 + (h * 2 + ksl) * 1024),
                       pf[ksl].s8, oacc1);
  }

  // ---- epilogue: combine k-halves via LDS, normalize (lane's q=l31), store ----
  __syncthreads();   // all waves done reading K/V stages
  union o16 { float16_t v; float4_t q[4]; };
  float* const FA = (float*)SM;
  float* const fb = FA + (size_t)(qw * 64 + lane) * 34;   // 34 f x 256 = 34816 B
  if (h == 1) {
    o16 a; a.v = oacc0;
    o16 b2; b2.v = oacc1;
#pragma unroll
    for (int i = 0; i < 4; ++i) *(float4_t*)(fb + i * 4)      = a.q[i];
#pragma unroll
    for (int i = 0; i < 4; ++i) *(float4_t*)(fb + 16 + i * 4) = b2.q[i];
    fb[32] = lacc[0];   // valid on hi=0 lanes (C row 0 of ones-MFMA)
  }
  __syncthreads();
  if (h == 0) {
    o16 a; a.v = oacc0;
    o16 b2; b2.v = oacc1;
#pragma unroll
    for (int i = 0; i < 4; ++i) {
      const float4_t p0 = *(const float4_t*)(fb + i * 4);
      const float4_t p1 = *(const float4_t*)(fb + 16 + i * 4);
      a.q[i][0] += p0[0]; a.q[i][1] += p0[1]; a.q[i][2] += p0[2]; a.q[i][3] += p0[3];
      b2.q[i][0] += p1[0]; b2.q[i][1] += p1[1]; b2.q[i][2] += p1[2]; b2.q[i][3] += p1[3];
    }
    // lsum: per-lane partial valid on hi=0; final broadcast reads lane l31<32.
    const float lsc = lacc[0] + fb[32];
    const float lst = __shfl(lsc, l31, 64);   // lane l31 is hi=0 -> valid
    const float inv = 1.0f / lst;
    const size_t ob = qb + (size_t)(q0 + qw * 32 + l31);
#pragma unroll
    for (int r = 0; r < 16; ++r) {
      const int drow = (r & 3) + 8 * (r >> 2) + 4 * hi;
      outg[ob + (size_t)(drow) * SEQ]      = a.v[r] * inv;
      outg[ob + (size_t)(drow + 32) * SEQ] = b2.v[r] * inv;
    }
  }
}

// ---------------- fallback (ws too small): R2-style, known-good ----------------
#define DPAD  72
#define PPAD  68
__global__ __launch_bounds__(256, 5)
void eia_attn_fb(const float* __restrict__ qg, const float* __restrict__ kg,
                 const float* __restrict__ vg, const int* __restrict__ klen,
                 float* __restrict__ outg) {
  __shared__ __align__(16) short QPs[64 * DPAD];
  __shared__ __align__(16) short Ksf[64 * DPAD];
  __shared__ __align__(16) short Vsf[64 * DPAD];

  const int tid  = threadIdx.x;
  const int bh   = blockIdx.x & 31;
  const int qt   = blockIdx.x >> 5;
  const int q0   = qt * 64;
  const int w    = tid >> 6;
  const int lane = tid & 63;
  const int quad = lane >> 4;
  const int l16  = lane & 15;

  const size_t base = (size_t)bh * 64 * SEQ;
  const float c = (1.4426950408889634f / (8.0f * 2.9957322735539909f)) *
                  logf((float)klen[bh >> 3]);

#pragma unroll
  for (int it = 0; it < 2; ++it) {
    const int e = it * 4 + w;
    float f[8];
#pragma unroll
    for (int j = 0; j < 8; ++j)
      f[j] = c * qg[base + (size_t)(e * 8 + j) * SEQ + (size_t)(q0 + lane)];
    union { short8_t s8; unsigned u[4]; } t;
#pragma unroll
    for (int j = 0; j < 4; ++j) t.u[j] = f2bf2u(f[2 * j], f[2 * j + 1]);
    *(short8_t*)&QPs[lane * DPAD + e * 8] = t.s8;
  }
  __syncthreads();

  short8_t qfrag[2];
#pragma unroll
  for (int s = 0; s < 2; ++s)
    qfrag[s] = *(const short8_t*)&QPs[(w * 16 + l16) * DPAD + s * 32 + quad * 8];

  float4_t oacc[4];
#pragma unroll
  for (int t = 0; t < 4; ++t) { oacc[t][0] = 0.f; oacc[t][1] = 0.f; oacc[t][2] = 0.f; oacc[t][3] = 0.f; }
  float lsumv[4] = {0.f, 0.f, 0.f, 0.f};
  const int pbase = w * (16 * DPAD);

  for (int kt = 0; kt < NKT; ++kt) {
    const int k0 = kt * 64;
#pragma unroll
    for (int it = 0; it < 2; ++it) {
      float f[8];
#pragma unroll
      for (int j = 0; j < 8; ++j)
        f[j] = kg[base + (size_t)((it * 4 + w) * 8 + j) * SEQ + (size_t)(k0 + lane)];
      union { short8_t s8; unsigned u[4]; } t;
#pragma unroll
      for (int j = 0; j < 4; ++j) t.u[j] = f2bf2u(f[2 * j], f[2 * j + 1]);
      *(short8_t*)&Ksf[lane * DPAD + (it * 4 + w) * 8] = t.s8;
    }
#pragma unroll
    for (int it = 0; it < 4; ++it) {
      const int d = it * 16 + (w << 2) + (lane >> 4);
      const float4_t vv = *(const float4_t*)&vg[base + (size_t)d * SEQ + (size_t)(k0 + ((lane & 15) << 2))];
      union { short4_t s4; unsigned u[2]; } t;
      t.u[0] = f2bf2u(vv[0], vv[1]);
      t.u[1] = f2bf2u(vv[2], vv[3]);
      *(short4_t*)&Vsf[d * DPAD + ((lane & 15) << 2)] = t.s4;
    }
    __syncthreads();

    float4_t sacc[4];
#pragma unroll
    for (int t = 0; t < 4; ++t) { sacc[t][0] = 0.f; sacc[t][1] = 0.f; sacc[t][2] = 0.f; sacc[t][3] = 0.f; }
#pragma unroll
    for (int t = 0; t < 4; ++t)
#pragma unroll
      for (int s = 0; s < 2; ++s) {
        const short8_t bf = *(const short8_t*)&Ksf[(t * 16 + l16) * DPAD + s * 32 + quad * 8];
        sacc[t] = mfma32(qfrag[s], bf, sacc[t]);
      }

#pragma unroll
    for (int r = 0; r < 4; ++r) {
      const float p0 = fast_exp2(sacc[0][r]);
      const float p1 = fast_exp2(sacc[1][r]);
      const float p2 = fast_exp2(sacc[2][r]);
      const float p3 = fast_exp2(sacc[3][r]);
      lsumv[r] += (p0 + p1) + (p2 + p3);
      const int prow = pbase + (quad * 4 + r) * PPAD + l16;
      QPs[prow +  0] = f2bf1(p0);
      QPs[prow + 16] = f2bf1(p1);
      QPs[prow + 32] = f2bf1(p2);
      QPs[prow + 48] = f2bf1(p3);
    }

#pragma unroll
    for (int s = 0; s < 2; ++s) {
      const short* pr = &QPs[pbase + l16 * PPAD + s * 32 + quad * 8];
      const short4_t plo = *(const short4_t*)pr;
      const short4_t phi = *(const short4_t*)(pr + 4);
      const short8_t pfv = {plo[0], plo[1], plo[2], plo[3], phi[0], phi[1], phi[2], phi[3]};
#pragma unroll
      for (int t = 0; t < 4; ++t) {
        const short8_t vf = *(const short8_t*)&Vsf[(t * 16 + l16) * DPAD + s * 32 + quad * 8];
        oacc[t] = mfma32(pfv, vf, oacc[t]);
      }
    }
    __syncthreads();
  }

  float inv[4];
#pragma unroll
  for (int r = 0; r < 4; ++r) {
    float v = lsumv[r];
    v += __shfl_xor(v, 1);
    v += __shfl_xor(v, 2);
    v += __shfl_xor(v, 4);
    v += __shfl_xor(v, 8);
    inv[r] = 1.0f / v;
  }
#pragma unroll
  for (int t = 0; t < 4; ++t)
#pragma unroll
    for (int r = 0; r < 4; ++r)
      outg[base + (size_t)(t * 16 + l16) * SEQ +
           (size_t)(q0 + w * 16 + quad * 4 + r)] = oacc[t][r] * inv[r];
}

extern "C" void kernel_launch(void* const* d_in, const int* in_sizes, int n_in,
                              void* d_out, int out_size, void* d_ws, size_t ws_size,
                              hipStream_t stream) {
  const float* q  = (const float*)d_in[0];
  const float* k  = (const float*)d_in[1];
  const float* v  = (const float*)d_in[2];
  const int*   kl = (const int*)d_in[3];
  float* out = (float*)d_out;

  const size_t TEN  = (size_t)NBH * SEQ * 64;
  const size_t need = 2 * TEN * sizeof(unsigned short);  // 16.8 MB

  if (ws_size >= need) {
    unsigned short* Kt2 = (unsigned short*)d_ws;
    unsigned short* Vt2 = Kt2 + TEN;
    eia_prep_kernel<<<1024, 256, 0, stream>>>(k, v, Kt2, Vt2);
    eia_attn_kernel<<<512, 512, 0, stream>>>(q, Kt2, Vt2, kl, out);
  } else {
    eia_attn_fb<<<1024, 256, 0, stream>>>(q, k, v, kl, out);
  }
}

// Round 15
// 135.415 us; speedup vs baseline: 1.0155x; 1.0155x over previous
//
#include <hip/hip_runtime.h>
#include <hip/hip_bf16.h>
#include <math.h>

// EntropyInvarianceAttention: out = softmax(c * Q^T K) V^T per (b,h),
// c = ln(k_length[b]) / (8*ln(20)); q,k,v are (B, 512, 2048) fp32, l contiguous.
//
// R22 = R20 (VERIFIED BEST: attn 49.4us / total 134.5us; 512x512, 8 waves =
// 4 q-subtiles x 2 k-halves, 3-stage LDS, asm cvt_pk, VALU lsum) + EXACTLY
// ONE delta:
//  - T5 s_setprio(1) around the QK and PV MFMA clusters (not exp). R20's CU
//    hosts 2 INDEPENDENT blocks (4 waves/SIMD, 2 per block) with unsynced
//    barrier domains -> the phase-diverse regime where m191 measured +4-7%
//    (m190's null was lockstep waves). First clean single-delta test here.
//  - R21 post-mortem: ones-MFMA lsum REVERTED (attn 49.4->52.1; the VALU
//    adds are epilogue-only, hidden under PV's MFMA shadow = free, while
//    the 2 extra chained MFMAs lengthened the matrix stream; MfmaUtil
//    28->35 confirmed). VALU lsum + R20 epilogue restored byte-identical.
// Prep (R13 fused) and fallback unchanged.

typedef __attribute__((ext_vector_type(8))) short short8_t;
typedef __attribute__((ext_vector_type(4))) short short4_t;
typedef __attribute__((ext_vector_type(4))) float float4_t;
typedef __attribute__((ext_vector_type(16))) float float16_t;

#define SEQ   2048
#define NBH   32
#define NKT   32

// pack two f32 -> one u32 of 2 bf16 (lo = a, hi = b), single instruction.
// T12/m201/m214 recipe (HW-refcheck'd); no builtin exists on gfx950.
__device__ __forceinline__ unsigned f2bf2u(float a, float b) {
  unsigned r;
  asm("v_cvt_pk_bf16_f32 %0, %1, %2" : "=v"(r) : "v"(a), "v"(b));
  return r;
}

__device__ __forceinline__ short f2bf1(float a) {
  return (short)(f2bf2u(a, a) & 0xffffu);
}

// 2^x via the builtin: compiler knows the trans-op hazard rules (R19 lesson:
// raw asm v_exp_f32 -> missing wait states -> stale reads -> wrong output).
__device__ __forceinline__ float fast_exp2(float x) {
#if __has_builtin(__builtin_amdgcn_exp2f)
  return __builtin_amdgcn_exp2f(x);
#else
  return exp2f(x);
#endif
}

__device__ __forceinline__ void gld16(const void* g, void* l) {
  __builtin_amdgcn_global_load_lds(
      (const __attribute__((address_space(1))) void*)g,
      (__attribute__((address_space(3))) void*)l, 16, 0, 0);
}

__device__ __forceinline__ float4_t mfma32(short8_t a, short8_t b, float4_t c) {
  return __builtin_amdgcn_mfma_f32_16x16x32_bf16(a, b, c, 0, 0, 0);
}

__device__ __forceinline__ float16_t mfma3232(short8_t a, short8_t b, float16_t c) {
  return __builtin_amdgcn_mfma_f32_32x32x16_bf16(a, b, c, 0, 0, 0);
}

// lane<32/lane>=32 half exchange: a' = [a_lo|b_lo], b' = [a_hi|b_hi]
__device__ __forceinline__ void plswap(unsigned& a, unsigned& b, int hi) {
#if __has_builtin(__builtin_amdgcn_permlane32_swap)
  typedef __attribute__((ext_vector_type(2))) unsigned uint2_t;
  uint2_t r = __builtin_amdgcn_permlane32_swap(a, b, false, false);
  a = r[0]; b = r[1];
#else
  const unsigned sa = (unsigned)__shfl_xor((int)a, 32);
  const unsigned sb = (unsigned)__shfl_xor((int)b, 32);
  const unsigned an = hi ? sb : a;
  const unsigned bn = hi ? b : sa;
  a = an; b = bn;
#endif
}

// ---------------- fused pre-pass (R13): one block per (bh,kt) ----------
// K -> Kt2[bh][kt][ch(8)][lr(64)][8]: out[ch*512+lr*8+j] = K[d=ch*8+j][k=lr]
// V -> Vt3[bh][kt][kc(8)][d(64)][8]:  out[(kc*64+d)*8+j] = V[d][k=kc*8+j]
#define PST 68
__global__ __launch_bounds__(256, 8)
void eia_prep_kernel(const float* __restrict__ kg, const float* __restrict__ vg,
                     unsigned short* __restrict__ Kt2, unsigned short* __restrict__ Vt2) {
  __shared__ __align__(16) short T[64 * PST];
  const int bh = blockIdx.x >> 5;
  const int kt = blockIdx.x & 31;
  const int t  = threadIdx.x;

  // ---- K phase: float4 loads along k, scatter bf16 to T[k][d] ----
  {
    const int dr = t >> 4;          // 0..15
    const int kq = (t & 15) * 4;    // 0,4,..,60
#pragma unroll
    for (int i = 0; i < 4; ++i) {
      const int d = i * 16 + dr;
      const float4_t f = *(const float4_t*)
          &kg[((size_t)bh * 64 + d) * SEQ + (size_t)(kt * 64 + kq)];
      T[(kq + 0) * PST + d] = f2bf1(f[0]);
      T[(kq + 1) * PST + d] = f2bf1(f[1]);
      T[(kq + 2) * PST + d] = f2bf1(f[2]);
      T[(kq + 3) * PST + d] = f2bf1(f[3]);
    }
  }
  __syncthreads();
  // K writeout (byte-identical to proven layout)
  {
    unsigned short* outt = Kt2 + (size_t)(bh * 32 + kt) * 4096;
#pragma unroll
    for (int rep = 0; rep < 2; ++rep) {
      const int id2 = rep * 256 + t;
      const int lr = id2 & 63, ch = id2 >> 6;
      union { short8_t v; short4_t h[2]; } o;
      o.h[0] = *(const short4_t*)&T[lr * PST + ch * 8];
      o.h[1] = *(const short4_t*)&T[lr * PST + ch * 8 + 4];
      *(short8_t*)&outt[ch * 512 + lr * 8] = o.v;
    }
  }
  __syncthreads();  // K reads of T done before V overwrites

  // ---- V phase: float4 loads along k into T[d][k] (proven pattern) ----
#pragma unroll
  for (int rep = 0; rep < 4; ++rep) {
    const int id2 = rep * 256 + t;
    const int d = id2 >> 4, l4 = (id2 & 15) * 4;
    const float4_t f = *(const float4_t*)
        &vg[((size_t)bh * 64 + d) * SEQ + (size_t)(kt * 64 + l4)];
    union { short4_t s; unsigned u[2]; } p;
    p.u[0] = f2bf2u(f[0], f[1]);
    p.u[1] = f2bf2u(f[2], f[3]);
    *(short4_t*)&T[d * PST + l4] = p.s;
  }
  __syncthreads();
  // Vt3 writeout (byte-identical to R12)
  {
    unsigned short* outt = Vt2 + (size_t)(bh * 32 + kt) * 4096;
#pragma unroll
    for (int rep = 0; rep < 2; ++rep) {
      const int c = rep * 256 + t;
      const int kc = c >> 6, d = c & 63;
      union { short8_t v; short4_t h[2]; } o;
      o.h[0] = *(const short4_t*)&T[d * PST + kc * 8];
      o.h[1] = *(const short4_t*)&T[d * PST + kc * 8 + 4];
      *(short8_t*)&outt[c * 8] = o.v;
    }
  }
}

// ---------------- main fused attention (R22: R20 + T5 setprio) ------------
// LDS (shorts): K stages [0,4096)|[4096,8192)|[8192,12288)
//               V stages [12288,16384)|[16384,20480)|[20480,24576)
// Q staging overlays [0, 8704); epilogue floats [0, 34816 B) after the loop.
__global__ __launch_bounds__(512, 4)
void eia_attn_kernel(const float* __restrict__ qg,
                     const unsigned short* __restrict__ Kt2,
                     const unsigned short* __restrict__ Vt2,
                     const int* __restrict__ klen,
                     float* __restrict__ outg) {
  __shared__ __align__(16) short SM[24576];

  const int tid   = threadIdx.x;
  const int bh    = blockIdx.x & 31;   // XCD = bh%8; 512 blocks = 2/CU
  const int qt    = blockIdx.x >> 5;
  const int q0    = qt * 128;
  const int wv    = tid >> 6;          // wave 0..7
  const int qw    = wv & 3;            // q-subtile (32 q)
  const int h     = wv >> 2;           // k-half: S-tile kb=h, ks=2h..2h+1
  const int lane  = tid & 63;
  const int l31   = lane & 31;
  const int hi    = lane >> 5;

  const float c = (1.4426950408889634f / (8.0f * 2.9957322735539909f)) *
                  logf((float)klen[bh >> 3]);
  const size_t qb = (size_t)bh * 64 * SEQ;

  // ---- Q stage: fp32 global -> SM[q][d] bf16 (stride 68), c folded ----
#pragma unroll
  for (int rep = 0; rep < 4; ++rep) {
    const int id = rep * 512 + tid;       // 0..2047
    const int d  = id >> 5;               // 0..63
    const int q4 = (id & 31) * 4;
    const float4_t f = *(const float4_t*)&qg[qb + (size_t)d * SEQ + (size_t)(q0 + q4)];
    SM[(q4 + 0) * 68 + d] = f2bf1(c * f[0]);
    SM[(q4 + 1) * 68 + d] = f2bf1(c * f[1]);
    SM[(q4 + 2) * 68 + d] = f2bf1(c * f[2]);
    SM[(q4 + 3) * 68 + d] = f2bf1(c * f[3]);
  }
  __syncthreads();

  // Q B-fragments (32x32x16 B-layout): B[d=s*16+hi*8+j][q=l31], s=0..3
  short8_t qfrag[4];
#pragma unroll
  for (int s = 0; s < 4; ++s) {
    const short* qp = &SM[(qw * 32 + l31) * 68 + s * 16 + hi * 8];
    const short4_t lo = *(const short4_t*)qp;
    const short4_t hh = *(const short4_t*)(qp + 4);
    qfrag[s] = short8_t{lo[0], lo[1], lo[2], lo[3], hh[0], hh[1], hh[2], hh[3]};
  }
  __syncthreads();  // Q reads done before DMA overwrites SM

  // ---- DMA setup: tile = 16 x 1KB instrs (8 K + 8 V) over 8 waves ----
  const char* ksrc = (const char*)Kt2 + (size_t)bh * NKT * 8192 + wv * 1024 + lane * 16;
  const char* vsrc = (const char*)Vt2 + (size_t)bh * NKT * 8192 + wv * 1024 + lane * 16;
  short* const kdst = &SM[wv * 512];            // + stage*4096 (HW adds lane*16B)
  short* const vdst = &SM[12288 + wv * 512];

  // per-lane invariant fragment offsets (shorts)
  const int lofs = hi * 512 + l31 * 8;
  const short* const kfp = &SM[lofs + h * 256];   // + koff + s*1024
  const short* const vfp = &SM[12288 + lofs];     // + koff + ks*1024 + dt*256

  const float16_t z16 = {0.f,0.f,0.f,0.f,0.f,0.f,0.f,0.f,
                         0.f,0.f,0.f,0.f,0.f,0.f,0.f,0.f};
  float16_t oacc0 = z16, oacc1 = z16;   // dt = 0,1 (k-half partials)
  float ls = 0.f;

  // ---- prologue: DMA tiles 0,1 -> stages 0,1 (2 loads/wave/tile) ----
  gld16(ksrc, kdst);               gld16(vsrc, vdst);
  gld16(ksrc + 8192, kdst + 4096); gld16(vsrc + 8192, vdst + 4096);
  // One-time full drain: no issue-order assumption on prologue loads.
  asm volatile("s_waitcnt vmcnt(0)" ::: "memory");

  int  sc = 0;              // stage (shorts offset/4096) of current tile
  int  sn = 2;              // stage of tile kt+2
  size_t gsrc = 2 * 8192;   // byte offset of tile kt+2

  for (int kt = 0; kt < NKT; ++kt) {
    // wait: current tile's 2 loads done; NEXT tile's 2 stay in flight.
    if (kt < NKT - 1) asm volatile("s_waitcnt vmcnt(2)" ::: "memory");
    else              asm volatile("s_waitcnt vmcnt(0)" ::: "memory");
    asm volatile("s_barrier" ::: "memory");

    // issue DMA for tile kt+2 into stage sn
    if (kt < NKT - 2) {
      const int so = sn * 4096;
      gld16(ksrc + gsrc, kdst + so);
      gld16(vsrc + gsrc, vdst + so);
      gsrc += 8192;
      sn = (sn == 2) ? 0 : sn + 1;
    }
    const int koff = sc * 4096;
    sc = (sc == 2) ? 0 : sc + 1;
    const short* const kb_ = kfp + koff;
    const short* const vb_ = vfp + koff;

    // ---- S^T = K^T * Q (this wave's kb-half): 4 chained mfma_32x32x16 ----
    // T5: boost this wave while it feeds the matrix pipe; the co-resident
    // block's waves are at an independent phase (exp/staging) -> m191 regime.
    __builtin_amdgcn_s_setprio(1);
    float16_t s0 = z16;
#pragma unroll
    for (int s = 0; s < 4; ++s)
      s0 = mfma3232(*(const short8_t*)(kb_ + s * 1024), qfrag[s], s0);
    __builtin_amdgcn_s_setprio(0);

    // ---- exp (builtin) + lsum (VALU, epilogue-only -> hidden) + repack ----
    float e[16];
#pragma unroll
    for (int r = 0; r < 16; ++r) e[r] = fast_exp2(s0[r]);
    ls += (((e[0] + e[1]) + (e[2] + e[3])) + ((e[4] + e[5]) + (e[6] + e[7]))) +
          (((e[8] + e[9]) + (e[10] + e[11])) + ((e[12] + e[13]) + (e[14] + e[15])));
    union pfu { short8_t s8; unsigned u[4]; };
    pfu pf[2];
#pragma unroll
    for (int ksl = 0; ksl < 2; ++ksl) {
      const int b = ksl * 8;
      unsigned a02 = f2bf2u(e[b + 0], e[b + 1]);
      unsigned b02 = f2bf2u(e[b + 4], e[b + 5]);
      unsigned a13 = f2bf2u(e[b + 2], e[b + 3]);
      unsigned b13 = f2bf2u(e[b + 6], e[b + 7]);
      plswap(a02, b02, hi);
      plswap(a13, b13, hi);
      pf[ksl].u[0] = a02;
      pf[ksl].u[1] = a13;
      pf[ksl].u[2] = b02;
      pf[ksl].u[3] = b13;
    }

    // ---- O^T += V * P^T (ks = 2h+ksl): 2 dt x 2 chained mfma_32x32x16 ----
    __builtin_amdgcn_s_setprio(1);
#pragma unroll
    for (int ksl = 0; ksl < 2; ++ksl)
      oacc0 = mfma3232(*(const short8_t*)(vb_ + (h * 2 + ksl) * 1024),
                       pf[ksl].s8, oacc0);
#pragma unroll
    for (int ksl = 0; ksl < 2; ++ksl)
      oacc1 = mfma3232(*(const short8_t*)(vb_ + 256 + (h * 2 + ksl) * 1024),
                       pf[ksl].s8, oacc1);
    __builtin_amdgcn_s_setprio(0);
  }

  // ---- epilogue: combine k-halves via LDS, normalize (lane's q=l31), store ----
  __syncthreads();   // all waves done reading K/V stages
  union o16 { float16_t v; float4_t q[4]; };
  float* const FA = (float*)SM;
  float* const fb = FA + (size_t)(qw * 64 + lane) * 34;   // 34 f x 256 = 34816 B
  if (h == 1) {
    o16 a; a.v = oacc0;
    o16 b2; b2.v = oacc1;
#pragma unroll
    for (int i = 0; i < 4; ++i) *(float4_t*)(fb + i * 4)      = a.q[i];
#pragma unroll
    for (int i = 0; i < 4; ++i) *(float4_t*)(fb + 16 + i * 4) = b2.q[i];
    fb[32] = ls;
  }
  __syncthreads();
  if (h == 0) {
    o16 a; a.v = oacc0;
    o16 b2; b2.v = oacc1;
#pragma unroll
    for (int i = 0; i < 4; ++i) {
      const float4_t p0 = *(const float4_t*)(fb + i * 4);
      const float4_t p1 = *(const float4_t*)(fb + 16 + i * 4);
      a.q[i][0] += p0[0]; a.q[i][1] += p0[1]; a.q[i][2] += p0[2]; a.q[i][3] += p0[3];
      b2.q[i][0] += p1[0]; b2.q[i][1] += p1[1]; b2.q[i][2] += p1[2]; b2.q[i][3] += p1[3];
    }
    const float lsc = ls + fb[32];
    const float lst = lsc + __shfl_xor(lsc, 32);
    const float inv = 1.0f / lst;
    const size_t ob = qb + (size_t)(q0 + qw * 32 + l31);
#pragma unroll
    for (int r = 0; r < 16; ++r) {
      const int drow = (r & 3) + 8 * (r >> 2) + 4 * hi;
      outg[ob + (size_t)(drow) * SEQ]      = a.v[r] * inv;
      outg[ob + (size_t)(drow + 32) * SEQ] = b2.v[r] * inv;
    }
  }
}

// ---------------- fallback (ws too small): R2-style, known-good ----------------
#define DPAD  72
#define PPAD  68
__global__ __launch_bounds__(256, 5)
void eia_attn_fb(const float* __restrict__ qg, const float* __restrict__ kg,
                 const float* __restrict__ vg, const int* __restrict__ klen,
                 float* __restrict__ outg) {
  __shared__ __align__(16) short QPs[64 * DPAD];
  __shared__ __align__(16) short Ksf[64 * DPAD];
  __shared__ __align__(16) short Vsf[64 * DPAD];

  const int tid  = threadIdx.x;
  const int bh   = blockIdx.x & 31;
  const int qt   = blockIdx.x >> 5;
  const int q0   = qt * 64;
  const int w    = tid >> 6;
  const int lane = tid & 63;
  const int quad = lane >> 4;
  const int l16  = lane & 15;

  const size_t base = (size_t)bh * 64 * SEQ;
  const float c = (1.4426950408889634f / (8.0f * 2.9957322735539909f)) *
                  logf((float)klen[bh >> 3]);

#pragma unroll
  for (int it = 0; it < 2; ++it) {
    const int e = it * 4 + w;
    float f[8];
#pragma unroll
    for (int j = 0; j < 8; ++j)
      f[j] = c * qg[base + (size_t)(e * 8 + j) * SEQ + (size_t)(q0 + lane)];
    union { short8_t s8; unsigned u[4]; } t;
#pragma unroll
    for (int j = 0; j < 4; ++j) t.u[j] = f2bf2u(f[2 * j], f[2 * j + 1]);
    *(short8_t*)&QPs[lane * DPAD + e * 8] = t.s8;
  }
  __syncthreads();

  short8_t qfrag[2];
#pragma unroll
  for (int s = 0; s < 2; ++s)
    qfrag[s] = *(const short8_t*)&QPs[(w * 16 + l16) * DPAD + s * 32 + quad * 8];

  float4_t oacc[4];
#pragma unroll
  for (int t = 0; t < 4; ++t) { oacc[t][0] = 0.f; oacc[t][1] = 0.f; oacc[t][2] = 0.f; oacc[t][3] = 0.f; }
  float lsumv[4] = {0.f, 0.f, 0.f, 0.f};
  const int pbase = w * (16 * DPAD);

  for (int kt = 0; kt < NKT; ++kt) {
    const int k0 = kt * 64;
#pragma unroll
    for (int it = 0; it < 2; ++it) {
      float f[8];
#pragma unroll
      for (int j = 0; j < 8; ++j)
        f[j] = kg[base + (size_t)((it * 4 + w) * 8 + j) * SEQ + (size_t)(k0 + lane)];
      union { short8_t s8; unsigned u[4]; } t;
#pragma unroll
      for (int j = 0; j < 4; ++j) t.u[j] = f2bf2u(f[2 * j], f[2 * j + 1]);
      *(short8_t*)&Ksf[lane * DPAD + (it * 4 + w) * 8] = t.s8;
    }
#pragma unroll
    for (int it = 0; it < 4; ++it) {
      const int d = it * 16 + (w << 2) + (lane >> 4);
      const float4_t vv = *(const float4_t*)&vg[base + (size_t)d * SEQ + (size_t)(k0 + ((lane & 15) << 2))];
      union { short4_t s4; unsigned u[2]; } t;
      t.u[0] = f2bf2u(vv[0], vv[1]);
      t.u[1] = f2bf2u(vv[2], vv[3]);
      *(short4_t*)&Vsf[d * DPAD + ((lane & 15) << 2)] = t.s4;
    }
    __syncthreads();

    float4_t sacc[4];
#pragma unroll
    for (int t = 0; t < 4; ++t) { sacc[t][0] = 0.f; sacc[t][1] = 0.f; sacc[t][2] = 0.f; sacc[t][3] = 0.f; }
#pragma unroll
    for (int t = 0; t < 4; ++t)
#pragma unroll
      for (int s = 0; s < 2; ++s) {
        const short8_t bf = *(const short8_t*)&Ksf[(t * 16 + l16) * DPAD + s * 32 + quad * 8];
        sacc[t] = mfma32(qfrag[s], bf, sacc[t]);
      }

#pragma unroll
    for (int r = 0; r < 4; ++r) {
      const float p0 = fast_exp2(sacc[0][r]);
      const float p1 = fast_exp2(sacc[1][r]);
      const float p2 = fast_exp2(sacc[2][r]);
      const float p3 = fast_exp2(sacc[3][r]);
      lsumv[r] += (p0 + p1) + (p2 + p3);
      const int prow = pbase + (quad * 4 + r) * PPAD + l16;
      QPs[prow +  0] = f2bf1(p0);
      QPs[prow + 16] = f2bf1(p1);
      QPs[prow + 32] = f2bf1(p2);
      QPs[prow + 48] = f2bf1(p3);
    }

#pragma unroll
    for (int s = 0; s < 2; ++s) {
      const short* pr = &QPs[pbase + l16 * PPAD + s * 32 + quad * 8];
      const short4_t plo = *(const short4_t*)pr;
      const short4_t phi = *(const short4_t*)(pr + 4);
      const short8_t pfv = {plo[0], plo[1], plo[2], plo[3], phi[0], phi[1], phi[2], phi[3]};
#pragma unroll
      for (int t = 0; t < 4; ++t) {
        const short8_t vf = *(const short8_t*)&Vsf[(t * 16 + l16) * DPAD + s * 32 + quad * 8];
        oacc[t] = mfma32(pfv, vf, oacc[t]);
      }
    }
    __syncthreads();
  }

  float inv[4];
#pragma unroll
  for (int r = 0; r < 4; ++r) {
    float v = lsumv[r];
    v += __shfl_xor(v, 1);
    v += __shfl_xor(v, 2);
    v += __shfl_xor(v, 4);
    v += __shfl_xor(v, 8);
    inv[r] = 1.0f / v;
  }
#pragma unroll
  for (int t = 0; t < 4; ++t)
#pragma unroll
    for (int r = 0; r < 4; ++r)
      outg[base + (size_t)(t * 16 + l16) * SEQ +
           (size_t)(q0 + w * 16 + quad * 4 + r)] = oacc[t][r] * inv[r];
}

extern "C" void kernel_launch(void* const* d_in, const int* in_sizes, int n_in,
                              void* d_out, int out_size, void* d_ws, size_t ws_size,
                              hipStream_t stream) {
  const float* q  = (const float*)d_in[0];
  const float* k  = (const float*)d_in[1];
  const float* v  = (const float*)d_in[2];
  const int*   kl = (const int*)d_in[3];
  float* out = (float*)d_out;

  const size_t TEN  = (size_t)NBH * SEQ * 64;
  const size_t need = 2 * TEN * sizeof(unsigned short);  // 16.8 MB

  if (ws_size >= need) {
    unsigned short* Kt2 = (unsigned short*)d_ws;
    unsigned short* Vt2 = Kt2 + TEN;
    eia_prep_kernel<<<1024, 256, 0, stream>>>(k, v, Kt2, Vt2);
    eia_attn_kernel<<<512, 512, 0, stream>>>(q, Kt2, Vt2, kl, out);
  } else {
    eia_attn_fb<<<1024, 256, 0, stream>>>(q, k, v, kl, out);
  }
}

// Round 16
// 134.067 us; speedup vs baseline: 1.0257x; 1.0101x over previous
//
#include <hip/hip_runtime.h>
#include <hip/hip_bf16.h>
#include <math.h>

// EntropyInvarianceAttention: out = softmax(c * Q^T K) V^T per (b,h),
// c = ln(k_length[b]) / (8*ln(20)); q,k,v are (B, 512, 2048) fp32, l contiguous.
//
// R23 = R20 byte-identical (VERIFIED SESSION BEST: attn 49.4us, total
// 134.5us). R22's setprio was neutral-to-slightly-negative (49.8 vs 49.4
// median) -> reverted. Final configuration:
//  - prep (R13): fused single-pass K/V -> tile-blocked swizzled bf16
//    workspace; float4 loads; ~BW-floor.
//  - attn (R17 structure + R20 helpers): 512 blocks x 512 thr; 8 waves =
//    4 q-subtiles (32q) x 2 k-halves; all-full-rate mfma_32x32x16 path
//    (QK 4 + PV 4 per wave-tile); 3-stage K|V LDS (48KB), 2 gld16/wave/tile,
//    prologue vmcnt(0) drain, steady vmcnt(2) + raw barrier, DMA(kt+2);
//    exp via __builtin_amdgcn_exp2f (compiler handles trans hazards);
//    P repack via 1-instr asm v_cvt_pk_bf16_f32 + permlane32_swap;
//    VALU lsum (epilogue-only, hidden under PV's MFMA shadow);
//    k-half combine via LDS epilogue, h=0 normalizes + stores.
// Session ledger: 141.6 -> 134.5us total (attn 62.5 -> 49.4). Wins:
// R10 wave-split (+6%), R13 prep rewrite, R17 4-waves/SIMD structure,
// R20 asm cvt_pk (-15%: kernel was VALU-issue-bound on the 7-instr
// emulated bf16 pack). Nulls: LDS traffic 4x cut, barrier pairing,
// phase domains, ones-MFMA lsum, setprio. Residual: ~36% dual-idle from
// the serial QK->exp->PV chain + barrier convoy; ~73us fixed harness
// overhead outside kernel control.

typedef __attribute__((ext_vector_type(8))) short short8_t;
typedef __attribute__((ext_vector_type(4))) short short4_t;
typedef __attribute__((ext_vector_type(4))) float float4_t;
typedef __attribute__((ext_vector_type(16))) float float16_t;

#define SEQ   2048
#define NBH   32
#define NKT   32

// pack two f32 -> one u32 of 2 bf16 (lo = a, hi = b), single instruction.
// T12/m201/m214 recipe (HW-refcheck'd); no builtin exists on gfx950.
__device__ __forceinline__ unsigned f2bf2u(float a, float b) {
  unsigned r;
  asm("v_cvt_pk_bf16_f32 %0, %1, %2" : "=v"(r) : "v"(a), "v"(b));
  return r;
}

__device__ __forceinline__ short f2bf1(float a) {
  return (short)(f2bf2u(a, a) & 0xffffu);
}

// 2^x via the builtin: compiler knows the trans-op hazard rules (R19 lesson:
// raw asm v_exp_f32 -> missing wait states -> stale reads -> wrong output).
__device__ __forceinline__ float fast_exp2(float x) {
#if __has_builtin(__builtin_amdgcn_exp2f)
  return __builtin_amdgcn_exp2f(x);
#else
  return exp2f(x);
#endif
}

__device__ __forceinline__ void gld16(const void* g, void* l) {
  __builtin_amdgcn_global_load_lds(
      (const __attribute__((address_space(1))) void*)g,
      (__attribute__((address_space(3))) void*)l, 16, 0, 0);
}

__device__ __forceinline__ float4_t mfma32(short8_t a, short8_t b, float4_t c) {
  return __builtin_amdgcn_mfma_f32_16x16x32_bf16(a, b, c, 0, 0, 0);
}

__device__ __forceinline__ float16_t mfma3232(short8_t a, short8_t b, float16_t c) {
  return __builtin_amdgcn_mfma_f32_32x32x16_bf16(a, b, c, 0, 0, 0);
}

// lane<32/lane>=32 half exchange: a' = [a_lo|b_lo], b' = [a_hi|b_hi]
__device__ __forceinline__ void plswap(unsigned& a, unsigned& b, int hi) {
#if __has_builtin(__builtin_amdgcn_permlane32_swap)
  typedef __attribute__((ext_vector_type(2))) unsigned uint2_t;
  uint2_t r = __builtin_amdgcn_permlane32_swap(a, b, false, false);
  a = r[0]; b = r[1];
#else
  const unsigned sa = (unsigned)__shfl_xor((int)a, 32);
  const unsigned sb = (unsigned)__shfl_xor((int)b, 32);
  const unsigned an = hi ? sb : a;
  const unsigned bn = hi ? b : sa;
  a = an; b = bn;
#endif
}

// ---------------- fused pre-pass (R13): one block per (bh,kt) ----------
// K -> Kt2[bh][kt][ch(8)][lr(64)][8]: out[ch*512+lr*8+j] = K[d=ch*8+j][k=lr]
// V -> Vt3[bh][kt][kc(8)][d(64)][8]:  out[(kc*64+d)*8+j] = V[d][k=kc*8+j]
#define PST 68
__global__ __launch_bounds__(256, 8)
void eia_prep_kernel(const float* __restrict__ kg, const float* __restrict__ vg,
                     unsigned short* __restrict__ Kt2, unsigned short* __restrict__ Vt2) {
  __shared__ __align__(16) short T[64 * PST];
  const int bh = blockIdx.x >> 5;
  const int kt = blockIdx.x & 31;
  const int t  = threadIdx.x;

  // ---- K phase: float4 loads along k, scatter bf16 to T[k][d] ----
  {
    const int dr = t >> 4;          // 0..15
    const int kq = (t & 15) * 4;    // 0,4,..,60
#pragma unroll
    for (int i = 0; i < 4; ++i) {
      const int d = i * 16 + dr;
      const float4_t f = *(const float4_t*)
          &kg[((size_t)bh * 64 + d) * SEQ + (size_t)(kt * 64 + kq)];
      T[(kq + 0) * PST + d] = f2bf1(f[0]);
      T[(kq + 1) * PST + d] = f2bf1(f[1]);
      T[(kq + 2) * PST + d] = f2bf1(f[2]);
      T[(kq + 3) * PST + d] = f2bf1(f[3]);
    }
  }
  __syncthreads();
  // K writeout (byte-identical to proven layout)
  {
    unsigned short* outt = Kt2 + (size_t)(bh * 32 + kt) * 4096;
#pragma unroll
    for (int rep = 0; rep < 2; ++rep) {
      const int id2 = rep * 256 + t;
      const int lr = id2 & 63, ch = id2 >> 6;
      union { short8_t v; short4_t h[2]; } o;
      o.h[0] = *(const short4_t*)&T[lr * PST + ch * 8];
      o.h[1] = *(const short4_t*)&T[lr * PST + ch * 8 + 4];
      *(short8_t*)&outt[ch * 512 + lr * 8] = o.v;
    }
  }
  __syncthreads();  // K reads of T done before V overwrites

  // ---- V phase: float4 loads along k into T[d][k] (proven pattern) ----
#pragma unroll
  for (int rep = 0; rep < 4; ++rep) {
    const int id2 = rep * 256 + t;
    const int d = id2 >> 4, l4 = (id2 & 15) * 4;
    const float4_t f = *(const float4_t*)
        &vg[((size_t)bh * 64 + d) * SEQ + (size_t)(kt * 64 + l4)];
    union { short4_t s; unsigned u[2]; } p;
    p.u[0] = f2bf2u(f[0], f[1]);
    p.u[1] = f2bf2u(f[2], f[3]);
    *(short4_t*)&T[d * PST + l4] = p.s;
  }
  __syncthreads();
  // Vt3 writeout (byte-identical to R12)
  {
    unsigned short* outt = Vt2 + (size_t)(bh * 32 + kt) * 4096;
#pragma unroll
    for (int rep = 0; rep < 2; ++rep) {
      const int c = rep * 256 + t;
      const int kc = c >> 6, d = c & 63;
      union { short8_t v; short4_t h[2]; } o;
      o.h[0] = *(const short4_t*)&T[d * PST + kc * 8];
      o.h[1] = *(const short4_t*)&T[d * PST + kc * 8 + 4];
      *(short8_t*)&outt[c * 8] = o.v;
    }
  }
}

// ---------------- main fused attention (R20 final) ------------------------
// LDS (shorts): K stages [0,4096)|[4096,8192)|[8192,12288)
//               V stages [12288,16384)|[16384,20480)|[20480,24576)
// Q staging overlays [0, 8704); epilogue floats [0, 34816 B) after the loop.
__global__ __launch_bounds__(512, 4)
void eia_attn_kernel(const float* __restrict__ qg,
                     const unsigned short* __restrict__ Kt2,
                     const unsigned short* __restrict__ Vt2,
                     const int* __restrict__ klen,
                     float* __restrict__ outg) {
  __shared__ __align__(16) short SM[24576];

  const int tid   = threadIdx.x;
  const int bh    = blockIdx.x & 31;   // XCD = bh%8; 512 blocks = 2/CU
  const int qt    = blockIdx.x >> 5;
  const int q0    = qt * 128;
  const int wv    = tid >> 6;          // wave 0..7
  const int qw    = wv & 3;            // q-subtile (32 q)
  const int h     = wv >> 2;           // k-half: S-tile kb=h, ks=2h..2h+1
  const int lane  = tid & 63;
  const int l31   = lane & 31;
  const int hi    = lane >> 5;

  const float c = (1.4426950408889634f / (8.0f * 2.9957322735539909f)) *
                  logf((float)klen[bh >> 3]);
  const size_t qb = (size_t)bh * 64 * SEQ;

  // ---- Q stage: fp32 global -> SM[q][d] bf16 (stride 68), c folded ----
#pragma unroll
  for (int rep = 0; rep < 4; ++rep) {
    const int id = rep * 512 + tid;       // 0..2047
    const int d  = id >> 5;               // 0..63
    const int q4 = (id & 31) * 4;
    const float4_t f = *(const float4_t*)&qg[qb + (size_t)d * SEQ + (size_t)(q0 + q4)];
    SM[(q4 + 0) * 68 + d] = f2bf1(c * f[0]);
    SM[(q4 + 1) * 68 + d] = f2bf1(c * f[1]);
    SM[(q4 + 2) * 68 + d] = f2bf1(c * f[2]);
    SM[(q4 + 3) * 68 + d] = f2bf1(c * f[3]);
  }
  __syncthreads();

  // Q B-fragments (32x32x16 B-layout): B[d=s*16+hi*8+j][q=l31], s=0..3
  short8_t qfrag[4];
#pragma unroll
  for (int s = 0; s < 4; ++s) {
    const short* qp = &SM[(qw * 32 + l31) * 68 + s * 16 + hi * 8];
    const short4_t lo = *(const short4_t*)qp;
    const short4_t hh = *(const short4_t*)(qp + 4);
    qfrag[s] = short8_t{lo[0], lo[1], lo[2], lo[3], hh[0], hh[1], hh[2], hh[3]};
  }
  __syncthreads();  // Q reads done before DMA overwrites SM

  // ---- DMA setup: tile = 16 x 1KB instrs (8 K + 8 V) over 8 waves ----
  const char* ksrc = (const char*)Kt2 + (size_t)bh * NKT * 8192 + wv * 1024 + lane * 16;
  const char* vsrc = (const char*)Vt2 + (size_t)bh * NKT * 8192 + wv * 1024 + lane * 16;
  short* const kdst = &SM[wv * 512];            // + stage*4096 (HW adds lane*16B)
  short* const vdst = &SM[12288 + wv * 512];

  // per-lane invariant fragment offsets (shorts)
  const int lofs = hi * 512 + l31 * 8;
  const short* const kfp = &SM[lofs + h * 256];   // + koff + s*1024
  const short* const vfp = &SM[12288 + lofs];     // + koff + ks*1024 + dt*256

  const float16_t z16 = {0.f,0.f,0.f,0.f,0.f,0.f,0.f,0.f,
                         0.f,0.f,0.f,0.f,0.f,0.f,0.f,0.f};
  float16_t oacc0 = z16, oacc1 = z16;   // dt = 0,1 (k-half partials)
  float ls = 0.f;

  // ---- prologue: DMA tiles 0,1 -> stages 0,1 (2 loads/wave/tile) ----
  gld16(ksrc, kdst);               gld16(vsrc, vdst);
  gld16(ksrc + 8192, kdst + 4096); gld16(vsrc + 8192, vdst + 4096);
  // One-time full drain: no issue-order assumption on prologue loads.
  asm volatile("s_waitcnt vmcnt(0)" ::: "memory");

  int  sc = 0;              // stage (shorts offset/4096) of current tile
  int  sn = 2;              // stage of tile kt+2
  size_t gsrc = 2 * 8192;   // byte offset of tile kt+2

  for (int kt = 0; kt < NKT; ++kt) {
    // wait: current tile's 2 loads done; NEXT tile's 2 stay in flight.
    if (kt < NKT - 1) asm volatile("s_waitcnt vmcnt(2)" ::: "memory");
    else              asm volatile("s_waitcnt vmcnt(0)" ::: "memory");
    asm volatile("s_barrier" ::: "memory");

    // issue DMA for tile kt+2 into stage sn
    if (kt < NKT - 2) {
      const int so = sn * 4096;
      gld16(ksrc + gsrc, kdst + so);
      gld16(vsrc + gsrc, vdst + so);
      gsrc += 8192;
      sn = (sn == 2) ? 0 : sn + 1;
    }
    const int koff = sc * 4096;
    sc = (sc == 2) ? 0 : sc + 1;
    const short* const kb_ = kfp + koff;
    const short* const vb_ = vfp + koff;

    // ---- S^T = K^T * Q (this wave's kb-half): 4 chained mfma_32x32x16 ----
    float16_t s0 = z16;
#pragma unroll
    for (int s = 0; s < 4; ++s)
      s0 = mfma3232(*(const short8_t*)(kb_ + s * 1024), qfrag[s], s0);

    // ---- exp (builtin) + lsum (VALU, epilogue-only -> hidden) + repack ----
    float e[16];
#pragma unroll
    for (int r = 0; r < 16; ++r) e[r] = fast_exp2(s0[r]);
    ls += (((e[0] + e[1]) + (e[2] + e[3])) + ((e[4] + e[5]) + (e[6] + e[7]))) +
          (((e[8] + e[9]) + (e[10] + e[11])) + ((e[12] + e[13]) + (e[14] + e[15])));
    union pfu { short8_t s8; unsigned u[4]; };
    pfu pf[2];
#pragma unroll
    for (int ksl = 0; ksl < 2; ++ksl) {
      const int b = ksl * 8;
      unsigned a02 = f2bf2u(e[b + 0], e[b + 1]);
      unsigned b02 = f2bf2u(e[b + 4], e[b + 5]);
      unsigned a13 = f2bf2u(e[b + 2], e[b + 3]);
      unsigned b13 = f2bf2u(e[b + 6], e[b + 7]);
      plswap(a02, b02, hi);
      plswap(a13, b13, hi);
      pf[ksl].u[0] = a02;
      pf[ksl].u[1] = a13;
      pf[ksl].u[2] = b02;
      pf[ksl].u[3] = b13;
    }

    // ---- O^T += V * P^T (ks = 2h+ksl): 2 dt x 2 chained mfma_32x32x16 ----
#pragma unroll
    for (int ksl = 0; ksl < 2; ++ksl)
      oacc0 = mfma3232(*(const short8_t*)(vb_ + (h * 2 + ksl) * 1024),
                       pf[ksl].s8, oacc0);
#pragma unroll
    for (int ksl = 0; ksl < 2; ++ksl)
      oacc1 = mfma3232(*(const short8_t*)(vb_ + 256 + (h * 2 + ksl) * 1024),
                       pf[ksl].s8, oacc1);
  }

  // ---- epilogue: combine k-halves via LDS, normalize (lane's q=l31), store ----
  __syncthreads();   // all waves done reading K/V stages
  union o16 { float16_t v; float4_t q[4]; };
  float* const FA = (float*)SM;
  float* const fb = FA + (size_t)(qw * 64 + lane) * 34;   // 34 f x 256 = 34816 B
  if (h == 1) {
    o16 a; a.v = oacc0;
    o16 b2; b2.v = oacc1;
#pragma unroll
    for (int i = 0; i < 4; ++i) *(float4_t*)(fb + i * 4)      = a.q[i];
#pragma unroll
    for (int i = 0; i < 4; ++i) *(float4_t*)(fb + 16 + i * 4) = b2.q[i];
    fb[32] = ls;
  }
  __syncthreads();
  if (h == 0) {
    o16 a; a.v = oacc0;
    o16 b2; b2.v = oacc1;
#pragma unroll
    for (int i = 0; i < 4; ++i) {
      const float4_t p0 = *(const float4_t*)(fb + i * 4);
      const float4_t p1 = *(const float4_t*)(fb + 16 + i * 4);
      a.q[i][0] += p0[0]; a.q[i][1] += p0[1]; a.q[i][2] += p0[2]; a.q[i][3] += p0[3];
      b2.q[i][0] += p1[0]; b2.q[i][1] += p1[1]; b2.q[i][2] += p1[2]; b2.q[i][3] += p1[3];
    }
    const float lsc = ls + fb[32];
    const float lst = lsc + __shfl_xor(lsc, 32);
    const float inv = 1.0f / lst;
    const size_t ob = qb + (size_t)(q0 + qw * 32 + l31);
#pragma unroll
    for (int r = 0; r < 16; ++r) {
      const int drow = (r & 3) + 8 * (r >> 2) + 4 * hi;
      outg[ob + (size_t)(drow) * SEQ]      = a.v[r] * inv;
      outg[ob + (size_t)(drow + 32) * SEQ] = b2.v[r] * inv;
    }
  }
}

// ---------------- fallback (ws too small): R2-style, known-good ----------------
#define DPAD  72
#define PPAD  68
__global__ __launch_bounds__(256, 5)
void eia_attn_fb(const float* __restrict__ qg, const float* __restrict__ kg,
                 const float* __restrict__ vg, const int* __restrict__ klen,
                 float* __restrict__ outg) {
  __shared__ __align__(16) short QPs[64 * DPAD];
  __shared__ __align__(16) short Ksf[64 * DPAD];
  __shared__ __align__(16) short Vsf[64 * DPAD];

  const int tid  = threadIdx.x;
  const int bh   = blockIdx.x & 31;
  const int qt   = blockIdx.x >> 5;
  const int q0   = qt * 64;
  const int w    = tid >> 6;
  const int lane = tid & 63;
  const int quad = lane >> 4;
  const int l16  = lane & 15;

  const size_t base = (size_t)bh * 64 * SEQ;
  const float c = (1.4426950408889634f / (8.0f * 2.9957322735539909f)) *
                  logf((float)klen[bh >> 3]);

#pragma unroll
  for (int it = 0; it < 2; ++it) {
    const int e = it * 4 + w;
    float f[8];
#pragma unroll
    for (int j = 0; j < 8; ++j)
      f[j] = c * qg[base + (size_t)(e * 8 + j) * SEQ + (size_t)(q0 + lane)];
    union { short8_t s8; unsigned u[4]; } t;
#pragma unroll
    for (int j = 0; j < 4; ++j) t.u[j] = f2bf2u(f[2 * j], f[2 * j + 1]);
    *(short8_t*)&QPs[lane * DPAD + e * 8] = t.s8;
  }
  __syncthreads();

  short8_t qfrag[2];
#pragma unroll
  for (int s = 0; s < 2; ++s)
    qfrag[s] = *(const short8_t*)&QPs[(w * 16 + l16) * DPAD + s * 32 + quad * 8];

  float4_t oacc[4];
#pragma unroll
  for (int t = 0; t < 4; ++t) { oacc[t][0] = 0.f; oacc[t][1] = 0.f; oacc[t][2] = 0.f; oacc[t][3] = 0.f; }
  float lsumv[4] = {0.f, 0.f, 0.f, 0.f};
  const int pbase = w * (16 * DPAD);

  for (int kt = 0; kt < NKT; ++kt) {
    const int k0 = kt * 64;
#pragma unroll
    for (int it = 0; it < 2; ++it) {
      float f[8];
#pragma unroll
      for (int j = 0; j < 8; ++j)
        f[j] = kg[base + (size_t)((it * 4 + w) * 8 + j) * SEQ + (size_t)(k0 + lane)];
      union { short8_t s8; unsigned u[4]; } t;
#pragma unroll
      for (int j = 0; j < 4; ++j) t.u[j] = f2bf2u(f[2 * j], f[2 * j + 1]);
      *(short8_t*)&Ksf[lane * DPAD + (it * 4 + w) * 8] = t.s8;
    }
#pragma unroll
    for (int it = 0; it < 4; ++it) {
      const int d = it * 16 + (w << 2) + (lane >> 4);
      const float4_t vv = *(const float4_t*)&vg[base + (size_t)d * SEQ + (size_t)(k0 + ((lane & 15) << 2))];
      union { short4_t s4; unsigned u[2]; } t;
      t.u[0] = f2bf2u(vv[0], vv[1]);
      t.u[1] = f2bf2u(vv[2], vv[3]);
      *(short4_t*)&Vsf[d * DPAD + ((lane & 15) << 2)] = t.s4;
    }
    __syncthreads();

    float4_t sacc[4];
#pragma unroll
    for (int t = 0; t < 4; ++t) { sacc[t][0] = 0.f; sacc[t][1] = 0.f; sacc[t][2] = 0.f; sacc[t][3] = 0.f; }
#pragma unroll
    for (int t = 0; t < 4; ++t)
#pragma unroll
      for (int s = 0; s < 2; ++s) {
        const short8_t bf = *(const short8_t*)&Ksf[(t * 16 + l16) * DPAD + s * 32 + quad * 8];
        sacc[t] = mfma32(qfrag[s], bf, sacc[t]);
      }

#pragma unroll
    for (int r = 0; r < 4; ++r) {
      const float p0 = fast_exp2(sacc[0][r]);
      const float p1 = fast_exp2(sacc[1][r]);
      const float p2 = fast_exp2(sacc[2][r]);
      const float p3 = fast_exp2(sacc[3][r]);
      lsumv[r] += (p0 + p1) + (p2 + p3);
      const int prow = pbase + (quad * 4 + r) * PPAD + l16;
      QPs[prow +  0] = f2bf1(p0);
      QPs[prow + 16] = f2bf1(p1);
      QPs[prow + 32] = f2bf1(p2);
      QPs[prow + 48] = f2bf1(p3);
    }

#pragma unroll
    for (int s = 0; s < 2; ++s) {
      const short* pr = &QPs[pbase + l16 * PPAD + s * 32 + quad * 8];
      const short4_t plo = *(const short4_t*)pr;
      const short4_t phi = *(const short4_t*)(pr + 4);
      const short8_t pfv = {plo[0], plo[1], plo[2], plo[3], phi[0], phi[1], phi[2], phi[3]};
#pragma unroll
      for (int t = 0; t < 4; ++t) {
        const short8_t vf = *(const short8_t*)&Vsf[(t * 16 + l16) * DPAD + s * 32 + quad * 8];
        oacc[t] = mfma32(pfv, vf, oacc[t]);
      }
    }
    __syncthreads();
  }

  float inv[4];
#pragma unroll
  for (int r = 0; r < 4; ++r) {
    float v = lsumv[r];
    v += __shfl_xor(v, 1);
    v += __shfl_xor(v, 2);
    v += __shfl_xor(v, 4);
    v += __shfl_xor(v, 8);
    inv[r] = 1.0f / v;
  }
#pragma unroll
  for (int t = 0; t < 4; ++t)
#pragma unroll
    for (int r = 0; r < 4; ++r)
      outg[base + (size_t)(t * 16 + l16) * SEQ +
           (size_t)(q0 + w * 16 + quad * 4 + r)] = oacc[t][r] * inv[r];
}

extern "C" void kernel_launch(void* const* d_in, const int* in_sizes, int n_in,
                              void* d_out, int out_size, void* d_ws, size_t ws_size,
                              hipStream_t stream) {
  const float* q  = (const float*)d_in[0];
  const float* k  = (const float*)d_in[1];
  const float* v  = (const float*)d_in[2];
  const int*   kl = (const int*)d_in[3];
  float* out = (float*)d_out;

  const size_t TEN  = (size_t)NBH * SEQ * 64;
  const size_t need = 2 * TEN * sizeof(unsigned short);  // 16.8 MB

  if (ws_size >= need) {
    unsigned short* Kt2 = (unsigned short*)d_ws;
    unsigned short* Vt2 = Kt2 + TEN;
    eia_prep_kernel<<<1024, 256, 0, stream>>>(k, v, Kt2, Vt2);
    eia_attn_kernel<<<512, 512, 0, stream>>>(q, Kt2, Vt2, kl, out);
  } else {
    eia_attn_fb<<<1024, 256, 0, stream>>>(q, k, v, kl, out);
  }
}